// Round 4
// baseline (2035.687 us; speedup 1.0000x reference)
//
#include <hip/hip_runtime.h>
#include <math.h>

constexpr int NB = 32, NT = 64, ND = 32, NH = 256, NZ = 64, NG = 768;

// ---- ws layout (float offsets; u16 regions noted) --------------------------
constexpr long long OFF_HENC   = 0;                               // [32][256] f32 (enc h master + final)
constexpr long long OFF_H0     = OFF_HENC + NB * NH;              // [32][256] f32
constexpr long long OFF_HDEC   = OFF_H0 + NB * NH;                // [32d][32b][256] f32 dec h master
constexpr long long OFF_BCMB   = OFF_HDEC + (long long)ND * NB * NH; // [32d][2][256]
constexpr long long OFF_BIN    = OFF_BCMB + ND * 2 * NH;          // [32d][256]
constexpr long long OFF_BHN    = OFF_BIN + ND * NH;               // [32d][256]
constexpr long long OFF_EBC    = OFF_BHN + ND * NH;               // [2][256]+[256]+[256] enc biases
constexpr long long OFF_WHHIMG = OFF_EBC + 1024;                  // u16: 256 pages x 24576 (swizzled bf16)
constexpr long long OFF_WCIMG  = OFF_WHHIMG + (long long)256 * 24576 / 2; // u16: 256 x 3072
constexpr long long OFF_DINIMG = OFF_WCIMG + 256 * 3072 / 2;      // u16: 64 x 1024
constexpr long long OFF_HBF    = OFF_DINIMG + 64 * 1024 / 2;      // u16: 2 par x 32 d x 8192
constexpr long long OFF_EW2    = OFF_HBF + 2 * 32 * 8192 / 2;     // u16: 8 pages x 24576 (enc Whh)
constexpr long long OFF_EWI2   = OFF_EW2 + 8 * 24576 / 2;         // u16: 8 pages x 3072 (enc Wih)
constexpr long long OFF_EXIMG  = OFF_EWI2 + 8 * 3072 / 2;         // u16: 64 pages x 1024 (x_past)
constexpr long long OFF_EHBF   = OFF_EXIMG + 64 * 1024 / 2;       // u16: 2 par x 8192 (enc h bf16)
constexpr long long OFF_SYNC   = OFF_EHBF + 2 * 8192 / 2;         // 1024 u32 barrier counters
constexpr long long WS_FLOATS  = OFF_SYNC + 1024;                 // ~17.2 MB

typedef __attribute__((ext_vector_type(8))) short bf16x8;
typedef __attribute__((ext_vector_type(4))) float f32x4;

__device__ __forceinline__ float sigm(float x) { return 1.f / (1.f + __expf(-x)); }
__device__ __forceinline__ ushort f2b(float x) {
  unsigned u = __float_as_uint(x);
  unsigned r = (u + 0x7FFFu + ((u >> 16) & 1u)) >> 16;
  return (ushort)r;
}
__device__ __forceinline__ unsigned syld(unsigned* p) {
  return __hip_atomic_load(p, __ATOMIC_ACQUIRE, __HIP_MEMORY_SCOPE_AGENT);
}

// ---------------- k_pre: weight images (dec + enc) + biases -------------------
__global__ void k_pre(const float* __restrict__ hWhh, const float* __restrict__ hbih,
                      const float* __restrict__ hbhh, const float* __restrict__ eWhh,
                      const float* __restrict__ eWih, const float* __restrict__ ebih,
                      const float* __restrict__ ebhh, float* __restrict__ ws) {
  int stride = gridDim.x * blockDim.x;
  int idx = blockIdx.x * blockDim.x + threadIdx.x;
  // (1) decoder Whh bf16 swizzled images: 256 pages x 12288 dwords
  unsigned* img = (unsigned*)(ws + OFF_WHHIMG);
  for (int i = idx; i < 256 * 12288; i += stride) {
    int p = i / 12288, lw = i - p * 12288;
    int d = p >> 3, s = p & 7;
    int byte = lw * 4;
    int lr = byte >> 9;
    int nominal = byte ^ ((lr & 7) << 4);
    int k0 = (nominal & 511) >> 1;
    int g = (lr >> 5) * 256 + s * 32 + (lr & 31);
    const float* src = hWhh + ((long long)(d * NG + g)) * NH + k0;
    img[i] = (unsigned)f2b(src[0]) | ((unsigned)f2b(src[1]) << 16);
  }
  // (2) decoder biases
  for (int i = idx; i < ND * NH; i += stride) {
    int d = i >> 8, j = i & 255;
    const float* bi = hbih + d * NG;
    const float* bh = hbhh + d * NG;
    ws[OFF_BCMB + d * 512 + j]       = bi[j] + bh[j];
    ws[OFF_BCMB + d * 512 + 256 + j] = bi[256 + j] + bh[256 + j];
    ws[OFF_BIN + i] = bi[512 + j];
    ws[OFF_BHN + i] = bh[512 + j];
  }
  // (3) encoder Whh images: 8 pages x 12288 dwords (same format as decoder)
  unsigned* eimg = (unsigned*)(ws + OFF_EW2);
  for (int i = idx; i < 8 * 12288; i += stride) {
    int s = i / 12288, lw = i - s * 12288;
    int byte = lw * 4;
    int lr = byte >> 9;
    int nominal = byte ^ ((lr & 7) << 4);
    int k0 = (nominal & 511) >> 1;
    int g = (lr >> 5) * 256 + s * 32 + (lr & 31);
    const float* src = eWhh + (long long)g * NH + k0;
    eimg[i] = (unsigned)f2b(src[0]) | ((unsigned)f2b(src[1]) << 16);
  }
  // (4) encoder Wih images: 8 pages x 1536 dwords (wc format: [96 rows][32 k])
  unsigned* eimg2 = (unsigned*)(ws + OFF_EWI2);
  for (int i = idx; i < 8 * 1536; i += stride) {
    int s = i / 1536, lw = i - s * 1536;
    int byte = lw * 4;
    int lr = byte >> 6;
    int nominal = byte ^ ((lr & 3) << 4);
    int dd0 = (nominal & 63) >> 1;
    int g = (lr >> 5) * 256 + s * 32 + (lr & 31);
    const float* src = eWih + g * 32 + dd0;
    eimg2[i] = (unsigned)f2b(src[0]) | ((unsigned)f2b(src[1]) << 16);
  }
  // (5) encoder biases
  for (int i = idx; i < 256; i += stride) {
    ws[OFF_EBC + i]       = ebih[i] + ebhh[i];
    ws[OFF_EBC + 256 + i] = ebih[256 + i] + ebhh[256 + i];
    ws[OFF_EBC + 512 + i] = ebih[512 + i];
    ws[OFF_EBC + 768 + i] = ebhh[512 + i];
  }
}

// ---------------- k_wcomb: Wcomb[d][g][dd] = sum_h Wih[g,h]*Win[dd,h] --------
__global__ __launch_bounds__(256)
void k_wcomb(const float* __restrict__ Win, const float* __restrict__ hWih,
             float* __restrict__ ws) {
  __shared__ float wd_s[32 * 257];
  __shared__ float wih_s[32 * 257];
  int blk = blockIdx.x;            // 768 = 32 d x 24 gsec
  int d = blk / 24, gsec = blk - d * 24;
  int tid = threadIdx.x;
  for (int i = tid; i < 32 * 256; i += 256) {
    int r = i >> 8, h = i & 255;
    wd_s[r * 257 + h]  = Win[((long long)(d * 32 + r)) * 256 + h];
    wih_s[r * 257 + h] = hWih[((long long)(d * NG + gsec * 32 + r)) * 256 + h];
  }
  __syncthreads();
  ushort* wcimg = (ushort*)(ws + OFF_WCIMG);
  for (int o = tid; o < 1024; o += 256) {
    int gl = o >> 5, dd = o & 31;
    float acc = 0.f;
    #pragma unroll 4
    for (int h = 0; h < 256; ++h) acc += wih_s[gl * 257 + h] * wd_s[dd * 257 + h];
    int gloc = gsec * 32 + gl;
    int sec = gloc >> 8, s = (gloc & 255) >> 5, lr = sec * 32 + (gloc & 31);
    int off = (lr * 64 + dd * 2) ^ ((lr & 3) << 4);
    wcimg[(d * 8 + s) * 3072 + (off >> 1)] = f2b(acc);
  }
}

// ---------------- k_misc: out init + din/x images + EHBF0 + sync zero ---------
__global__ void k_misc(const float* __restrict__ xp, const float* __restrict__ xc,
                       const float* __restrict__ fcb, float* __restrict__ ws,
                       float* __restrict__ out) {
  int idx = blockIdx.x * blockDim.x + threadIdx.x;   // 0..136191
  if (idx < 65536) {
    out[idx] = fcb[idx & 31];
  } else if (idx < 98304) {
    int i2 = idx - 65536;                      // din image: 64 t x 512 dwords
    int t = i2 >> 9, lw = i2 & 511;
    int byte = lw * 4;
    int b = byte >> 6;
    int nominal = byte ^ ((b & 3) << 4);
    int dd0 = (nominal & 63) >> 1;
    float v0, v1;
    if (t == 0) { v0 = xp[(b * NT + 63) * ND + dd0]; v1 = xp[(b * NT + 63) * ND + dd0 + 1]; }
    else { v0 = xc[(b * NT + (t - 1)) * ND + dd0]; v1 = xc[(b * NT + (t - 1)) * ND + dd0 + 1]; }
    ((unsigned*)(ws + OFF_DINIMG))[i2] = (unsigned)f2b(v0) | ((unsigned)f2b(v1) << 16);
  } else if (idx < 131072) {
    int i3 = idx - 98304;                      // enc x image: 64 t x 512 dwords
    int t = i3 >> 9, lw = i3 & 511;
    int byte = lw * 4;
    int b = byte >> 6;
    int nominal = byte ^ ((b & 3) << 4);
    int dd0 = (nominal & 63) >> 1;
    float v0 = xp[(b * NT + t) * ND + dd0];
    float v1 = xp[(b * NT + t) * ND + dd0 + 1];
    ((unsigned*)(ws + OFF_EXIMG))[i3] = (unsigned)f2b(v0) | ((unsigned)f2b(v1) << 16);
  } else if (idx < 135168) {
    ((unsigned*)(ws + OFF_EHBF))[idx - 131072] = 0;   // enc h parity-0 page = 0
  } else {
    ((unsigned*)(ws + OFF_SYNC))[idx - 135168] = 0;   // barrier counters
  }
}

// ---------------- k_enc3: persistent encoder, 8 j-slice blocks ----------------
// Weights LDS-resident (staged once). Per step: stage h(16KB)+x(2KB), MFMA,
// gate math, XCD-local spin barrier (workers at blockIdx%8==0 -> one XCD).
__global__ __launch_bounds__(384)
void k_enc3(float* __restrict__ ws) {
  if (blockIdx.x & 7) return;                  // 8 workers of 64 blocks
  __shared__ __align__(16) char lds[49152 + 6144 + 16384 + 2048];
  __shared__ float rz_s[64 * 33];
  __shared__ float in_s[32 * 33];
  __shared__ float ahn_s[32 * 33];
  char* l_whh = lds;
  char* l_wi  = lds + 49152;
  char* l_hbf = lds + 49152 + 6144;
  char* l_x   = lds + 49152 + 6144 + 16384;

  const int s = blockIdx.x >> 3;
  const int tid = threadIdx.x, lane = tid & 63, w = tid >> 6;

  // stage weights once
  {
    const uint4* sw = (const uint4*)((const ushort*)(ws + OFF_EW2) + s * 24576);
    const uint4* si = (const uint4*)((const ushort*)(ws + OFF_EWI2) + s * 3072);
    uint4* dw = (uint4*)l_whh; uint4* di = (uint4*)l_wi;
    for (int c = tid; c < 3456; c += 384) {
      if (c < 3072) dw[c] = sw[c];
      else          di[c - 3072] = si[c - 3072];
    }
  }

  const float* ebc = ws + OFF_EBC;
  unsigned* ecnt = (unsigned*)(ws + OFF_SYNC) + 512;
  const int ct = w & 1, rtb = w >> 1;
  const int colL = lane & 15;
  const int kb = (lane >> 4) * 16;

  for (int t = 0; t < 64; ++t) {
    const int par = t & 1;
    { // stage h + x
      const uint4* sh = (const uint4*)((const ushort*)(ws + OFF_EHBF) + par * 8192);
      const uint4* sx = (const uint4*)((const ushort*)(ws + OFF_EXIMG) + t * 1024);
      uint4* dh = (uint4*)l_hbf; uint4* dx = (uint4*)l_x;
      for (int c = tid; c < 1152; c += 384) {
        if (c < 1024) dh[c] = sh[c];
        else          dx[c - 1024] = sx[c - 1024];
      }
    }
    __syncthreads();

    #pragma unroll
    for (int i = 0; i < 2; ++i) {
      int rtx = rtb + 3 * i;
      int rowW = rtx * 16 + colL;
      int rowB = ct * 16 + colL;
      f32x4 ah = {0.f, 0.f, 0.f, 0.f};
      #pragma unroll
      for (int kc = 0; kc < 8; ++kc) {
        int ka = kc * 64 + kb;
        bf16x8 av = *(const bf16x8*)(l_whh + ((rowW * 512 + ka) ^ ((rowW & 7) << 4)));
        bf16x8 bv = *(const bf16x8*)(l_hbf + ((rowB * 512 + ka) ^ ((rowB & 7) << 4)));
        ah = __builtin_amdgcn_mfma_f32_16x16x32_bf16(av, bv, ah, 0, 0, 0);
      }
      f32x4 zero = {0.f, 0.f, 0.f, 0.f};
      bf16x8 aw = *(const bf16x8*)(l_wi + ((rowW * 64 + kb) ^ ((rowW & 3) << 4)));
      bf16x8 bd = *(const bf16x8*)(l_x + ((rowB * 64 + kb) ^ ((rowB & 3) << 4)));
      f32x4 ai = __builtin_amdgcn_mfma_f32_16x16x32_bf16(aw, bd, zero, 0, 0, 0);
      int r0 = rtx * 16 + (lane >> 4) * 4;
      int col = ct * 16 + colL;
      #pragma unroll
      for (int rg = 0; rg < 4; ++rg) {
        int lr = r0 + rg;
        if (lr < 64) rz_s[lr * 33 + col] = ah[rg] + ai[rg];
        else { in_s[(lr - 64) * 33 + col] = ai[rg]; ahn_s[(lr - 64) * 33 + col] = ah[rg]; }
      }
    }
    __syncthreads();

    ushort* ehw = (ushort*)(ws + OFF_EHBF) + (par ^ 1) * 8192;
    for (int base = 0; base < 1024; base += 384) {
      int idx = base + tid;
      if (idx < 1024) {
        int bb = idx >> 5, jl = idx & 31, jg = s * 32 + jl;
        float pr = rz_s[jl * 33 + bb] + ebc[jg];
        float pz = rz_s[(32 + jl) * 33 + bb] + ebc[256 + jg];
        float pni = in_s[jl * 33 + bb] + ebc[512 + jg];
        float pnh = ahn_s[jl * 33 + bb] + ebc[768 + jg];
        float r = sigm(pr), u = sigm(pz);
        float n = tanhf(pni + r * pnh);
        float hold = (t == 0) ? 0.f : ws[OFF_HENC + bb * 256 + jg];
        float hnew = (1.f - u) * n + u * hold;
        ws[OFF_HENC + bb * 256 + jg] = hnew;
        int bo = (bb * 512 + jg * 2) ^ ((bb & 7) << 4);
        ehw[bo >> 1] = f2b(hnew);
      }
    }
    __syncthreads();
    // 8-block barrier
    if (tid == 0) {
      __threadfence();
      atomicAdd(ecnt, 1u);
      while (syld(ecnt) < 8u * (t + 1)) {}
      __threadfence();
    }
    __syncthreads();
  }
}

// ---------------- latent ------------------------------------------------------
__global__ __launch_bounds__(256)
void k_latent(const float* __restrict__ muw, const float* __restrict__ mub,
              const float* __restrict__ lsw, const float* __restrict__ lsb,
              const float* __restrict__ refw, const float* __restrict__ refb,
              const float* __restrict__ eps, float* __restrict__ ws,
              float* __restrict__ out) {
  __shared__ float hs[NH];
  __shared__ float mu_s[NZ];
  __shared__ float ls_s[NZ];
  __shared__ float zs[NZ];
  int b = blockIdx.x, tid = threadIdx.x;
  hs[tid] = ws[OFF_HENC + b * NH + tid];
  __syncthreads();
  if (tid < 128) {
    int zi = tid & 63;
    const float* w = (tid < 64 ? muw : lsw) + zi * NH;
    float acc = 0.f;
    #pragma unroll 4
    for (int k = 0; k < NH; ++k) acc += w[k] * hs[k];
    if (tid < 64) {
      acc += mub[zi];
      out[NB * NT * ND + b * NZ + zi] = acc;
      mu_s[zi] = acc;
    } else {
      acc += lsb[zi];
      out[NB * NT * ND + NB * NZ + b * NZ + zi] = acc;
      ls_s[zi] = acc;
    }
  }
  __syncthreads();
  if (tid < 64) zs[tid] = mu_s[tid] + eps[b * NZ + tid] * __expf(ls_s[tid]);
  __syncthreads();
  {
    const float* w = refw + tid * NZ;
    float acc = 0.f;
    #pragma unroll 4
    for (int q = 0; q < NZ; ++q) acc += w[q] * zs[q];
    ws[OFF_H0 + b * NH + tid] = tanhf(acc + refb[tid]);
  }
}

// ---------------- k_hbf0: h0 -> bf16 swizzled pages (parity 0) ----------------
__global__ void k_hbf0(float* __restrict__ ws) {
  int idx = blockIdx.x * blockDim.x + threadIdx.x;   // 32 x 4096 dwords
  int d = idx >> 12, lw = idx & 4095;
  int byte = lw * 4;
  int bb = byte >> 9;
  int nominal = byte ^ ((bb & 7) << 4);
  int j0 = (nominal & 511) >> 1;
  const float* h0 = ws + OFF_H0 + bb * 256;
  ((unsigned*)(ws + OFF_HBF))[d * 4096 + lw] =
      (unsigned)f2b(h0[j0]) | ((unsigned)f2b(h0[j0 + 1]) << 16);
}

// ---------------- k_dec: persistent decoder, 256 blocks (8 slices x 32 heads) -
// Weights LDS-resident. Per step: stage h(16KB)+din(2KB), MFMA, gate, fc,
// two-level spin barrier (8 groups x 32 + 8-leader global).
__global__ __launch_bounds__(384)
void k_dec(const float* __restrict__ fcw, float* __restrict__ ws,
           float* __restrict__ out) {
  __shared__ __align__(16) char lds[49152 + 6144 + 16384 + 2048];
  __shared__ float rz_s[64 * 33];
  __shared__ float in_s[32 * 33];
  __shared__ float ahn_s[32 * 33];
  __shared__ float hn_s[32 * 33];
  char* l_whh = lds;
  char* l_wc  = lds + 49152;
  char* l_hbf = lds + 49152 + 6144;
  char* l_din = lds + 49152 + 6144 + 16384;

  const int d = blockIdx.x & 31, s = blockIdx.x >> 5;
  const int tid = threadIdx.x, lane = tid & 63, w = tid >> 6;

  { // stage weights once
    const uint4* sw = (const uint4*)((const ushort*)(ws + OFF_WHHIMG) + (long long)(d * 8 + s) * 24576);
    const uint4* sc = (const uint4*)((const ushort*)(ws + OFF_WCIMG) + (d * 8 + s) * 3072);
    uint4* dw = (uint4*)l_whh; uint4* dc = (uint4*)l_wc;
    for (int c = tid; c < 3456; c += 384) {
      if (c < 3072) dw[c] = sw[c];
      else          dc[c - 3072] = sc[c - 3072];
    }
  }

  const float* bcmb = ws + OFF_BCMB + d * 512;
  const float* bin  = ws + OFF_BIN + d * 256;
  const float* bhn  = ws + OFF_BHN + d * 256;
  float* hdec = ws + OFF_HDEC + (long long)d * NB * NH;
  const float* h0 = ws + OFF_H0;
  unsigned* sy = (unsigned*)(ws + OFF_SYNC);
  const unsigned x = blockIdx.x & 7;
  const int ct = w & 1, rtb = w >> 1;
  const int colL = lane & 15;
  const int kb = (lane >> 4) * 16;

  for (int t = 0; t < 64; ++t) {
    { // stage h + din
      const uint4* sh = (const uint4*)((const ushort*)(ws + OFF_HBF) + ((t & 1) * 32 + d) * 8192);
      const uint4* sx = (const uint4*)((const ushort*)(ws + OFF_DINIMG) + t * 1024);
      uint4* dh = (uint4*)l_hbf; uint4* dx = (uint4*)l_din;
      for (int c = tid; c < 1152; c += 384) {
        if (c < 1024) dh[c] = sh[c];
        else          dx[c - 1024] = sx[c - 1024];
      }
    }
    __syncthreads();

    #pragma unroll
    for (int i = 0; i < 2; ++i) {
      int rtx = rtb + 3 * i;
      int rowW = rtx * 16 + colL;
      int rowB = ct * 16 + colL;
      f32x4 ah = {0.f, 0.f, 0.f, 0.f};
      #pragma unroll
      for (int kc = 0; kc < 8; ++kc) {
        int ka = kc * 64 + kb;
        bf16x8 av = *(const bf16x8*)(l_whh + ((rowW * 512 + ka) ^ ((rowW & 7) << 4)));
        bf16x8 bv = *(const bf16x8*)(l_hbf + ((rowB * 512 + ka) ^ ((rowB & 7) << 4)));
        ah = __builtin_amdgcn_mfma_f32_16x16x32_bf16(av, bv, ah, 0, 0, 0);
      }
      f32x4 zero = {0.f, 0.f, 0.f, 0.f};
      bf16x8 aw = *(const bf16x8*)(l_wc + ((rowW * 64 + kb) ^ ((rowW & 3) << 4)));
      bf16x8 bd = *(const bf16x8*)(l_din + ((rowB * 64 + kb) ^ ((rowB & 3) << 4)));
      f32x4 ai = __builtin_amdgcn_mfma_f32_16x16x32_bf16(aw, bd, zero, 0, 0, 0);
      int r0 = rtx * 16 + (lane >> 4) * 4;
      int col = ct * 16 + colL;
      #pragma unroll
      for (int rg = 0; rg < 4; ++rg) {
        int lr = r0 + rg;
        if (lr < 64) rz_s[lr * 33 + col] = ah[rg] + ai[rg];
        else { in_s[(lr - 64) * 33 + col] = ai[rg]; ahn_s[(lr - 64) * 33 + col] = ah[rg]; }
      }
    }
    __syncthreads();

    ushort* hbf_w = (ushort*)(ws + OFF_HBF) + (((t + 1) & 1) * 32 + d) * 8192;
    for (int base = 0; base < 1024; base += 384) {
      int idx = base + tid;
      if (idx < 1024) {
        int bb = idx >> 5, jl = idx & 31, jg = s * 32 + jl;
        float pr = rz_s[jl * 33 + bb] + bcmb[jg];
        float pz = rz_s[(32 + jl) * 33 + bb] + bcmb[256 + jg];
        float pni = in_s[jl * 33 + bb] + bin[jg];
        float pnh = ahn_s[jl * 33 + bb] + bhn[jg];
        float r = sigm(pr), u = sigm(pz);
        float n = tanhf(pni + r * pnh);
        float hold = (t == 0) ? h0[bb * 256 + jg] : hdec[bb * 256 + jg];
        float hnew = (1.f - u) * n + u * hold;
        hdec[bb * 256 + jg] = hnew;
        hn_s[jl * 33 + bb] = hnew;
        int bo = (bb * 512 + jg * 2) ^ ((bb & 7) << 4);
        hbf_w[bo >> 1] = f2b(hnew);
      }
    }
    __syncthreads();

    if (tid < 32) {
      const float* fw = fcw + d * 256 + s * 32;
      float acc = 0.f;
      #pragma unroll
      for (int jl = 0; jl < 32; ++jl) acc += hn_s[jl * 33 + tid] * fw[jl];
      atomicAdd(&out[(tid * NT + t) * ND + d], acc);
    }

    // two-level device barrier
    if (tid == 0) {
      __threadfence();
      atomicAdd(&sy[x * 16], 1u);
      if (blockIdx.x < 8) {
        while (syld(&sy[x * 16]) < 32u * (t + 1)) {}
        atomicAdd(&sy[128], 1u);
        while (syld(&sy[128]) < 8u * (t + 1)) {}
        __hip_atomic_store(&sy[256 + x * 16], (unsigned)(t + 1),
                           __ATOMIC_RELEASE, __HIP_MEMORY_SCOPE_AGENT);
      } else {
        while (syld(&sy[256 + x * 16]) < (unsigned)(t + 1)) {}
      }
      __threadfence();
    }
    __syncthreads();
  }
}

extern "C" void kernel_launch(void* const* d_in, const int* in_sizes, int n_in,
                              void* d_out, int out_size, void* d_ws, size_t ws_size,
                              hipStream_t stream) {
  const float* x_past = (const float*)d_in[0];
  const float* x_curr = (const float*)d_in[1];
  const float* eps    = (const float*)d_in[2];
  const float* eWih   = (const float*)d_in[3];
  const float* ebih   = (const float*)d_in[4];
  const float* eWhh   = (const float*)d_in[5];
  const float* ebhh   = (const float*)d_in[6];
  const float* muw    = (const float*)d_in[7];
  const float* mub    = (const float*)d_in[8];
  const float* lsw    = (const float*)d_in[9];
  const float* lsb    = (const float*)d_in[10];
  const float* refw   = (const float*)d_in[11];
  const float* refb   = (const float*)d_in[12];
  const float* Win    = (const float*)d_in[13];
  const float* hWih   = (const float*)d_in[14];
  const float* hbih   = (const float*)d_in[15];
  const float* hWhh   = (const float*)d_in[16];
  const float* hbhh   = (const float*)d_in[17];
  const float* fcw    = (const float*)d_in[18];
  const float* fcb    = (const float*)d_in[19];
  float* ws  = (float*)d_ws;
  float* out = (float*)d_out;

  if (ws_size < (size_t)WS_FLOATS * 4) return;

  k_pre   <<<2048, 256, 0, stream>>>(hWhh, hbih, hbhh, eWhh, eWih, ebih, ebhh, ws);
  k_wcomb <<<768, 256, 0, stream>>>(Win, hWih, ws);
  k_misc  <<<532, 256, 0, stream>>>(x_past, x_curr, fcb, ws, out);
  k_enc3  <<<64, 384, 0, stream>>>(ws);
  k_latent<<<NB, 256, 0, stream>>>(muw, mub, lsw, lsb, refw, refb, eps, ws, out);
  k_hbf0  <<<512, 256, 0, stream>>>(ws);
  k_dec   <<<256, 384, 0, stream>>>(fcw, ws, out);
}

// Round 5
// 1043.368 us; speedup vs baseline: 1.9511x; 1.9511x over previous
//
#include <hip/hip_runtime.h>
#include <math.h>

constexpr int NB = 32, NT = 64, ND = 32, NH = 256, NZ = 64, NG = 768;

// ---- ws layout (float offsets; u16 regions noted) --------------------------
constexpr long long OFF_HENC   = 0;                               // [32][256] f32
constexpr long long OFF_H0     = OFF_HENC + NB * NH;              // [32][256] f32
constexpr long long OFF_HDEC   = OFF_H0 + NB * NH;                // [32d][32b][256] f32
constexpr long long OFF_BCMB   = OFF_HDEC + (long long)ND * NB * NH; // [32d][2][256]
constexpr long long OFF_BIN    = OFF_BCMB + ND * 2 * NH;          // [32d][256]
constexpr long long OFF_BHN    = OFF_BIN + ND * NH;               // [32d][256]
constexpr long long OFF_EBC    = OFF_BHN + ND * NH;               // enc biases [4][256]
constexpr long long OFF_WHHIMG = OFF_EBC + 1024;                  // u16: 128 pages x 49152 (192rows x 256k swz)
constexpr long long OFF_WCIMG  = OFF_WHHIMG + (long long)128 * 49152 / 2; // u16: 128 x 6144 (192x32 swz)
constexpr long long OFF_DINIMG = OFF_WCIMG + (long long)128 * 6144 / 2;   // u16: 64 x 1024
constexpr long long OFF_HBF    = OFF_DINIMG + 64 * 1024 / 2;      // u16: 2 par x 32 d x 8192
constexpr long long OFF_EW2    = OFF_HBF + 2 * 32 * 8192 / 2;     // u16: 4 pages x 49152
constexpr long long OFF_EWI2   = OFF_EW2 + 4 * 49152 / 2;         // u16: 4 x 6144
constexpr long long OFF_EXIMG  = OFF_EWI2 + 4 * 6144 / 2;         // u16: 64 x 1024
constexpr long long OFF_EHBF   = OFF_EXIMG + 64 * 1024 / 2;       // u16: 2 par x 8192
constexpr long long OFF_SYNC   = OFF_EHBF + 2 * 8192 / 2;         // 2048 u32
constexpr long long WS_FLOATS  = OFF_SYNC + 2048;                 // ~17.2 MB

typedef __attribute__((ext_vector_type(8))) short bf16x8;
typedef __attribute__((ext_vector_type(4))) float f32x4;

__device__ __forceinline__ float sigm(float x) { return 1.f / (1.f + __expf(-x)); }
__device__ __forceinline__ ushort f2b(float x) {
  unsigned u = __float_as_uint(x);
  unsigned r = (u + 0x7FFFu + ((u >> 16) & 1u)) >> 16;
  return (ushort)r;
}
// relaxed agent atomics: visible at device coherence point, NO cache flush/inv
__device__ __forceinline__ unsigned ld_cnt(unsigned* p) {
  return __hip_atomic_load(p, __ATOMIC_RELAXED, __HIP_MEMORY_SCOPE_AGENT);
}
__device__ __forceinline__ unsigned long long ld_h64(const unsigned long long* p) {
  return __hip_atomic_load(p, __ATOMIC_RELAXED, __HIP_MEMORY_SCOPE_AGENT);
}
__device__ __forceinline__ void st_h32(unsigned* p, unsigned v) {
  __hip_atomic_store(p, v, __ATOMIC_RELAXED, __HIP_MEMORY_SCOPE_AGENT);
}
// tid0-only: arrive (relaxed; prior stores drained by __syncthreads vmcnt(0)) + spin
__device__ __forceinline__ void arrive_wait(unsigned* cnt, unsigned target) {
  __hip_atomic_fetch_add(cnt, 1u, __ATOMIC_RELAXED, __HIP_MEMORY_SCOPE_AGENT);
  while (ld_cnt(cnt) < target) __builtin_amdgcn_s_sleep(2);
}

// ---------------- k_pre: weight images (dec + enc) + biases -------------------
__global__ void k_pre(const float* __restrict__ hWhh, const float* __restrict__ hbih,
                      const float* __restrict__ hbhh, const float* __restrict__ eWhh,
                      const float* __restrict__ eWih, const float* __restrict__ ebih,
                      const float* __restrict__ ebhh, float* __restrict__ ws) {
  int stride = gridDim.x * blockDim.x;
  int idx = blockIdx.x * blockDim.x + threadIdx.x;
  // (1) decoder Whh images: 128 pages (d,s2) x 24576 dwords; 192 rows x 256 k
  unsigned* img = (unsigned*)(ws + OFF_WHHIMG);
  for (int i = idx; i < 128 * 24576; i += stride) {
    int p = i / 24576, lw = i - p * 24576;
    int d = p >> 2, s2 = p & 3;
    int byte = lw * 4;
    int lr = byte >> 9;                        // 0..191
    int nominal = byte ^ ((lr & 7) << 4);
    int k0 = (nominal & 511) >> 1;
    int g = (lr >> 6) * 256 + s2 * 64 + (lr & 63);
    const float* src = hWhh + ((long long)(d * NG + g)) * NH + k0;
    img[i] = (unsigned)f2b(src[0]) | ((unsigned)f2b(src[1]) << 16);
  }
  // (2) decoder biases
  for (int i = idx; i < ND * NH; i += stride) {
    int d = i >> 8, j = i & 255;
    const float* bi = hbih + d * NG;
    const float* bh = hbhh + d * NG;
    ws[OFF_BCMB + d * 512 + j]       = bi[j] + bh[j];
    ws[OFF_BCMB + d * 512 + 256 + j] = bi[256 + j] + bh[256 + j];
    ws[OFF_BIN + i] = bi[512 + j];
    ws[OFF_BHN + i] = bh[512 + j];
  }
  // (3) encoder Whh images: 4 pages x 24576 dwords
  unsigned* eimg = (unsigned*)(ws + OFF_EW2);
  for (int i = idx; i < 4 * 24576; i += stride) {
    int s2 = i / 24576, lw = i - s2 * 24576;
    int byte = lw * 4;
    int lr = byte >> 9;
    int nominal = byte ^ ((lr & 7) << 4);
    int k0 = (nominal & 511) >> 1;
    int g = (lr >> 6) * 256 + s2 * 64 + (lr & 63);
    const float* src = eWhh + (long long)g * NH + k0;
    eimg[i] = (unsigned)f2b(src[0]) | ((unsigned)f2b(src[1]) << 16);
  }
  // (4) encoder Wih images: 4 pages x 3072 dwords (192 rows x 32 k)
  unsigned* eimg2 = (unsigned*)(ws + OFF_EWI2);
  for (int i = idx; i < 4 * 3072; i += stride) {
    int s2 = i / 3072, lw = i - s2 * 3072;
    int byte = lw * 4;
    int lr = byte >> 6;
    int nominal = byte ^ ((lr & 3) << 4);
    int dd0 = (nominal & 63) >> 1;
    int g = (lr >> 6) * 256 + s2 * 64 + (lr & 63);
    const float* src = eWih + g * 32 + dd0;
    eimg2[i] = (unsigned)f2b(src[0]) | ((unsigned)f2b(src[1]) << 16);
  }
  // (5) encoder biases
  for (int i = idx; i < 256; i += stride) {
    ws[OFF_EBC + i]       = ebih[i] + ebhh[i];
    ws[OFF_EBC + 256 + i] = ebih[256 + i] + ebhh[256 + i];
    ws[OFF_EBC + 512 + i] = ebih[512 + i];
    ws[OFF_EBC + 768 + i] = ebhh[512 + i];
  }
}

// ---------------- k_wcomb: Wcomb[d][g][dd] = sum_h Wih[g,h]*Win[dd,h] --------
__global__ __launch_bounds__(256)
void k_wcomb(const float* __restrict__ Win, const float* __restrict__ hWih,
             float* __restrict__ ws) {
  __shared__ float wd_s[32 * 257];
  __shared__ float wih_s[32 * 257];
  int blk = blockIdx.x;            // 768 = 32 d x 24 gsec
  int d = blk / 24, gsec = blk - d * 24;
  int tid = threadIdx.x;
  for (int i = tid; i < 32 * 256; i += 256) {
    int r = i >> 8, h = i & 255;
    wd_s[r * 257 + h]  = Win[((long long)(d * 32 + r)) * 256 + h];
    wih_s[r * 257 + h] = hWih[((long long)(d * NG + gsec * 32 + r)) * 256 + h];
  }
  __syncthreads();
  ushort* wcimg = (ushort*)(ws + OFF_WCIMG);
  for (int o = tid; o < 1024; o += 256) {
    int gl = o >> 5, dd = o & 31;
    float acc = 0.f;
    #pragma unroll 4
    for (int h = 0; h < 256; ++h) acc += wih_s[gl * 257 + h] * wd_s[dd * 257 + h];
    int g = gsec * 32 + gl;
    int s2 = (g & 255) >> 6, lr = (g >> 8) * 64 + (g & 63);
    int off = (lr * 64 + dd * 2) ^ ((lr & 3) << 4);
    wcimg[(d * 4 + s2) * 6144 + (off >> 1)] = f2b(acc);
  }
}

// ---------------- k_misc: out init + din/x images + EHBF0 + sync zero ---------
__global__ void k_misc(const float* __restrict__ xp, const float* __restrict__ xc,
                       const float* __restrict__ fcb, float* __restrict__ ws,
                       float* __restrict__ out) {
  int idx = blockIdx.x * blockDim.x + threadIdx.x;   // 0..137215
  if (idx < 65536) {
    out[idx] = fcb[idx & 31];
  } else if (idx < 98304) {
    int i2 = idx - 65536;                      // din image
    int t = i2 >> 9, lw = i2 & 511;
    int byte = lw * 4;
    int b = byte >> 6;
    int nominal = byte ^ ((b & 3) << 4);
    int dd0 = (nominal & 63) >> 1;
    float v0, v1;
    if (t == 0) { v0 = xp[(b * NT + 63) * ND + dd0]; v1 = xp[(b * NT + 63) * ND + dd0 + 1]; }
    else { v0 = xc[(b * NT + (t - 1)) * ND + dd0]; v1 = xc[(b * NT + (t - 1)) * ND + dd0 + 1]; }
    ((unsigned*)(ws + OFF_DINIMG))[i2] = (unsigned)f2b(v0) | ((unsigned)f2b(v1) << 16);
  } else if (idx < 131072) {
    int i3 = idx - 98304;                      // enc x image
    int t = i3 >> 9, lw = i3 & 511;
    int byte = lw * 4;
    int b = byte >> 6;
    int nominal = byte ^ ((b & 3) << 4);
    int dd0 = (nominal & 63) >> 1;
    float v0 = xp[(b * NT + t) * ND + dd0];
    float v1 = xp[(b * NT + t) * ND + dd0 + 1];
    ((unsigned*)(ws + OFF_EXIMG))[i3] = (unsigned)f2b(v0) | ((unsigned)f2b(v1) << 16);
  } else if (idx < 135168) {
    ((unsigned*)(ws + OFF_EHBF))[idx - 131072] = 0;   // enc h parity-0 = 0
  } else {
    ((unsigned*)(ws + OFF_SYNC))[idx - 135168] = 0;   // barrier counters
  }
}

// ---------------- shared step body pieces (macro-free, duplicated) ------------
// ---------------- k_enc4: persistent encoder, 4 j-slice blocks ----------------
__global__ __launch_bounds__(384)
void k_enc4(float* __restrict__ ws) {
  __shared__ __align__(16) char lds[98304 + 16384];
  __shared__ float rz_s[128 * 33];
  __shared__ float in_s[64 * 33];
  __shared__ float ahn_s[64 * 33];
  __shared__ float henc_s[32 * 65];
  char* l_whh = lds;
  char* l_hbf = lds + 98304;

  const int s2 = blockIdx.x;                   // 0..3
  const int tid = threadIdx.x, lane = tid & 63, w = tid >> 6;

  { // stage weights once
    const uint4* sw = (const uint4*)((const ushort*)(ws + OFF_EW2) + (long long)s2 * 49152);
    uint4* dw = (uint4*)l_whh;
    for (int c = tid; c < 6144; c += 384) dw[c] = sw[c];
  }
  for (int i = tid; i < 32 * 65; i += 384) henc_s[i] = 0.f;

  const ushort* wi_pg = (const ushort*)(ws + OFF_EWI2) + s2 * 6144;
  const float* ebc = ws + OFF_EBC;
  unsigned* cnt = (unsigned*)(ws + OFF_SYNC) + 1024;
  const int ct = w & 1, rtw = w >> 1;
  const int colL = lane & 15;
  const int kb = (lane >> 4) * 16;
  const int jbase = s2 * 64;

  for (int t = 0; t < 64; ++t) {
    { // stage h page (atomic u64: agent-visible regardless of XCD placement)
      const unsigned long long* hs =
          (const unsigned long long*)((const ushort*)(ws + OFF_EHBF) + (t & 1) * 8192);
      unsigned long long* hd = (unsigned long long*)l_hbf;
      for (int c = tid; c < 2048; c += 384) hd[c] = ld_h64(hs + c);
    }
    __syncthreads();

    const ushort* x_pg = (const ushort*)(ws + OFF_EXIMG) + t * 1024;
    #pragma unroll
    for (int i = 0; i < 4; ++i) {
      int rt = rtw + 3 * i;
      int rowW = rt * 16 + colL;
      int rowB = ct * 16 + colL;
      f32x4 ah = {0.f, 0.f, 0.f, 0.f};
      #pragma unroll
      for (int kc = 0; kc < 8; ++kc) {
        int ka = kc * 64 + kb;
        bf16x8 av = *(const bf16x8*)(l_whh + ((rowW * 512 + ka) ^ ((rowW & 7) << 4)));
        bf16x8 bv = *(const bf16x8*)(l_hbf + ((rowB * 512 + ka) ^ ((rowB & 7) << 4)));
        ah = __builtin_amdgcn_mfma_f32_16x16x32_bf16(av, bv, ah, 0, 0, 0);
      }
      f32x4 zero = {0.f, 0.f, 0.f, 0.f};
      bf16x8 aw = *(const bf16x8*)((const char*)wi_pg + ((rowW * 64 + kb) ^ ((rowW & 3) << 4)));
      bf16x8 bd = *(const bf16x8*)((const char*)x_pg + ((rowB * 64 + kb) ^ ((rowB & 3) << 4)));
      f32x4 ai = __builtin_amdgcn_mfma_f32_16x16x32_bf16(aw, bd, zero, 0, 0, 0);
      int r0 = rt * 16 + (lane >> 4) * 4;
      int col = ct * 16 + colL;
      #pragma unroll
      for (int rg = 0; rg < 4; ++rg) {
        int lr = r0 + rg;
        if (lr < 128) rz_s[lr * 33 + col] = ah[rg] + ai[rg];
        else { in_s[(lr - 128) * 33 + col] = ai[rg]; ahn_s[(lr - 128) * 33 + col] = ah[rg]; }
      }
    }
    __syncthreads();

    unsigned* hw32 = (unsigned*)((ushort*)(ws + OFF_EHBF) + ((t + 1) & 1) * 8192);
    for (int base = 0; base < 1024; base += 384) {
      int o = base + tid;
      if (o < 1024) {
        int bb = o >> 5, jp = o & 31, jl = 2 * jp, jg = jbase + jl;
        float h0n, h1n;
        #pragma unroll
        for (int q = 0; q < 2; ++q) {
          int j = jl + q;
          float pr = rz_s[j * 33 + bb] + ebc[jg + q];
          float pz = rz_s[(64 + j) * 33 + bb] + ebc[256 + jg + q];
          float pni = in_s[j * 33 + bb] + ebc[512 + jg + q];
          float pnh = ahn_s[j * 33 + bb] + ebc[768 + jg + q];
          float r = sigm(pr), u = sigm(pz);
          float n = tanhf(pni + r * pnh);
          float hold = henc_s[bb * 65 + j];
          float hv = (1.f - u) * n + u * hold;
          henc_s[bb * 65 + j] = hv;
          if (q == 0) h0n = hv; else h1n = hv;
        }
        int bo = (bb * 512 + jg * 2) ^ ((bb & 7) << 4);
        st_h32(hw32 + (bo >> 2), (unsigned)f2b(h0n) | ((unsigned)f2b(h1n) << 16));
      }
    }
    __syncthreads();   // drains vmcnt(0): h stores complete before arrival
    if (tid == 0) arrive_wait(cnt, 4u * (t + 1));
    __syncthreads();
  }
  // final hidden
  for (int o = tid; o < 2048; o += 384) {
    int bb = o >> 6, jl = o & 63;
    ws[OFF_HENC + bb * 256 + jbase + jl] = henc_s[bb * 65 + jl];
  }
}

// ---------------- latent ------------------------------------------------------
__global__ __launch_bounds__(256)
void k_latent(const float* __restrict__ muw, const float* __restrict__ mub,
              const float* __restrict__ lsw, const float* __restrict__ lsb,
              const float* __restrict__ refw, const float* __restrict__ refb,
              const float* __restrict__ eps, float* __restrict__ ws,
              float* __restrict__ out) {
  __shared__ float hs[NH];
  __shared__ float mu_s[NZ];
  __shared__ float ls_s[NZ];
  __shared__ float zs[NZ];
  int b = blockIdx.x, tid = threadIdx.x;
  hs[tid] = ws[OFF_HENC + b * NH + tid];
  __syncthreads();
  if (tid < 128) {
    int zi = tid & 63;
    const float* w = (tid < 64 ? muw : lsw) + zi * NH;
    float acc = 0.f;
    #pragma unroll 4
    for (int k = 0; k < NH; ++k) acc += w[k] * hs[k];
    if (tid < 64) {
      acc += mub[zi];
      out[NB * NT * ND + b * NZ + zi] = acc;
      mu_s[zi] = acc;
    } else {
      acc += lsb[zi];
      out[NB * NT * ND + NB * NZ + b * NZ + zi] = acc;
      ls_s[zi] = acc;
    }
  }
  __syncthreads();
  if (tid < 64) zs[tid] = mu_s[tid] + eps[b * NZ + tid] * __expf(ls_s[tid]);
  __syncthreads();
  {
    const float* w = refw + tid * NZ;
    float acc = 0.f;
    #pragma unroll 4
    for (int q = 0; q < NZ; ++q) acc += w[q] * zs[q];
    ws[OFF_H0 + b * NH + tid] = tanhf(acc + refb[tid]);
  }
}

// ---------------- k_hbf0: h0 -> dec h pages parity 0 --------------------------
__global__ void k_hbf0(float* __restrict__ ws) {
  int idx = blockIdx.x * blockDim.x + threadIdx.x;   // 32 x 4096 dwords
  int d = idx >> 12, lw = idx & 4095;
  int byte = lw * 4;
  int bb = byte >> 9;
  int nominal = byte ^ ((bb & 7) << 4);
  int j0 = (nominal & 511) >> 1;
  const float* h0 = ws + OFF_H0 + bb * 256;
  ((unsigned*)(ws + OFF_HBF))[d * 4096 + lw] =
      (unsigned)f2b(h0[j0]) | ((unsigned)f2b(h0[j0 + 1]) << 16);
}

// ---------------- k_dec: persistent decoder, 128 blocks = 4 slices x 32 heads -
__global__ __launch_bounds__(384)
void k_dec(const float* __restrict__ fcw, float* __restrict__ ws,
           float* __restrict__ out) {
  __shared__ __align__(16) char lds[98304 + 16384];
  __shared__ float rz_s[128 * 33];
  __shared__ float in_s[64 * 33];
  __shared__ float ahn_s[64 * 33];
  char* l_whh = lds;
  char* l_hbf = lds + 98304;

  const int d = blockIdx.x & 31, s2 = blockIdx.x >> 5;
  const int tid = threadIdx.x, lane = tid & 63, w = tid >> 6;

  { // stage weights once
    const uint4* sw = (const uint4*)((const ushort*)(ws + OFF_WHHIMG) + (long long)(d * 4 + s2) * 49152);
    uint4* dw = (uint4*)l_whh;
    for (int c = tid; c < 6144; c += 384) dw[c] = sw[c];
  }

  const ushort* wc_pg = (const ushort*)(ws + OFF_WCIMG) + (d * 4 + s2) * 6144;
  const float* bcmb = ws + OFF_BCMB + d * 512;
  const float* bin  = ws + OFF_BIN + d * 256;
  const float* bhn  = ws + OFF_BHN + d * 256;
  float* hdec = ws + OFF_HDEC + (long long)d * NB * NH;
  const float* h0 = ws + OFF_H0;
  unsigned* cnt = (unsigned*)(ws + OFF_SYNC) + d * 32;
  const int ct = w & 1, rtw = w >> 1;
  const int colL = lane & 15;
  const int kb = (lane >> 4) * 16;
  const int jbase = s2 * 64;

  for (int t = 0; t < 64; ++t) {
    { // stage h page (atomic u64)
      const unsigned long long* hs =
          (const unsigned long long*)((const ushort*)(ws + OFF_HBF) + ((t & 1) * 32 + d) * 8192);
      unsigned long long* hd = (unsigned long long*)l_hbf;
      for (int c = tid; c < 2048; c += 384) hd[c] = ld_h64(hs + c);
    }
    __syncthreads();

    const ushort* din_pg = (const ushort*)(ws + OFF_DINIMG) + t * 1024;
    #pragma unroll
    for (int i = 0; i < 4; ++i) {
      int rt = rtw + 3 * i;
      int rowW = rt * 16 + colL;
      int rowB = ct * 16 + colL;
      f32x4 ah = {0.f, 0.f, 0.f, 0.f};
      #pragma unroll
      for (int kc = 0; kc < 8; ++kc) {
        int ka = kc * 64 + kb;
        bf16x8 av = *(const bf16x8*)(l_whh + ((rowW * 512 + ka) ^ ((rowW & 7) << 4)));
        bf16x8 bv = *(const bf16x8*)(l_hbf + ((rowB * 512 + ka) ^ ((rowB & 7) << 4)));
        ah = __builtin_amdgcn_mfma_f32_16x16x32_bf16(av, bv, ah, 0, 0, 0);
      }
      f32x4 zero = {0.f, 0.f, 0.f, 0.f};
      bf16x8 aw = *(const bf16x8*)((const char*)wc_pg + ((rowW * 64 + kb) ^ ((rowW & 3) << 4)));
      bf16x8 bd = *(const bf16x8*)((const char*)din_pg + ((rowB * 64 + kb) ^ ((rowB & 3) << 4)));
      f32x4 ai = __builtin_amdgcn_mfma_f32_16x16x32_bf16(aw, bd, zero, 0, 0, 0);
      int r0 = rt * 16 + (lane >> 4) * 4;
      int col = ct * 16 + colL;
      #pragma unroll
      for (int rg = 0; rg < 4; ++rg) {
        int lr = r0 + rg;
        if (lr < 128) rz_s[lr * 33 + col] = ah[rg] + ai[rg];
        else { in_s[(lr - 128) * 33 + col] = ai[rg]; ahn_s[(lr - 128) * 33 + col] = ah[rg]; }
      }
    }
    __syncthreads();

    unsigned* hw32 = (unsigned*)((ushort*)(ws + OFF_HBF) + (((t + 1) & 1) * 32 + d) * 8192);
    for (int base = 0; base < 1024; base += 384) {
      int o = base + tid;
      if (o < 1024) {
        int bb = o >> 5, jp = o & 31, jl = 2 * jp, jg = jbase + jl;
        float h0n, h1n;
        #pragma unroll
        for (int q = 0; q < 2; ++q) {
          int j = jl + q;
          float pr = rz_s[j * 33 + bb] + bcmb[jg + q];
          float pz = rz_s[(64 + j) * 33 + bb] + bcmb[256 + jg + q];
          float pni = in_s[j * 33 + bb] + bin[jg + q];
          float pnh = ahn_s[j * 33 + bb] + bhn[jg + q];
          float r = sigm(pr), u = sigm(pz);
          float n = tanhf(pni + r * pnh);
          float hold = (t == 0) ? h0[bb * 256 + jg + q] : hdec[bb * 256 + jg + q];
          float hv = (1.f - u) * n + u * hold;
          hdec[bb * 256 + jg + q] = hv;
          in_s[j * 33 + bb] = hv;               // reuse in_s as hnew for fc
          if (q == 0) h0n = hv; else h1n = hv;
        }
        int bo = (bb * 512 + jg * 2) ^ ((bb & 7) << 4);
        st_h32(hw32 + (bo >> 2), (unsigned)f2b(h0n) | ((unsigned)f2b(h1n) << 16));
      }
    }
    __syncthreads();

    if (tid < 32) {
      const float* fw = fcw + d * 256 + jbase;
      float acc = 0.f;
      #pragma unroll
      for (int jl = 0; jl < 64; ++jl) acc += in_s[jl * 33 + tid] * fw[jl];
      atomicAdd(&out[(tid * NT + t) * ND + d], acc);
    }
    __syncthreads();   // drains all stores (vmcnt 0) before arrival
    if (tid == 0) arrive_wait(cnt, 4u * (t + 1));
    __syncthreads();
  }
}

extern "C" void kernel_launch(void* const* d_in, const int* in_sizes, int n_in,
                              void* d_out, int out_size, void* d_ws, size_t ws_size,
                              hipStream_t stream) {
  const float* x_past = (const float*)d_in[0];
  const float* x_curr = (const float*)d_in[1];
  const float* eps    = (const float*)d_in[2];
  const float* eWih   = (const float*)d_in[3];
  const float* ebih   = (const float*)d_in[4];
  const float* eWhh   = (const float*)d_in[5];
  const float* ebhh   = (const float*)d_in[6];
  const float* muw    = (const float*)d_in[7];
  const float* mub    = (const float*)d_in[8];
  const float* lsw    = (const float*)d_in[9];
  const float* lsb    = (const float*)d_in[10];
  const float* refw   = (const float*)d_in[11];
  const float* refb   = (const float*)d_in[12];
  const float* Win    = (const float*)d_in[13];
  const float* hWih   = (const float*)d_in[14];
  const float* hbih   = (const float*)d_in[15];
  const float* hWhh   = (const float*)d_in[16];
  const float* hbhh   = (const float*)d_in[17];
  const float* fcw    = (const float*)d_in[18];
  const float* fcb    = (const float*)d_in[19];
  float* ws  = (float*)d_ws;
  float* out = (float*)d_out;

  if (ws_size < (size_t)WS_FLOATS * 4) return;

  k_pre   <<<2048, 256, 0, stream>>>(hWhh, hbih, hbhh, eWhh, eWih, ebih, ebhh, ws);
  k_wcomb <<<768, 256, 0, stream>>>(Win, hWih, ws);
  k_misc  <<<536, 256, 0, stream>>>(x_past, x_curr, fcb, ws, out);
  k_enc4  <<<4, 384, 0, stream>>>(ws);
  k_latent<<<NB, 256, 0, stream>>>(muw, mub, lsw, lsb, refw, refb, eps, ws, out);
  k_hbf0  <<<512, 256, 0, stream>>>(ws);
  k_dec   <<<128, 384, 0, stream>>>(fcw, ws, out);
}

// Round 6
// 939.123 us; speedup vs baseline: 2.1676x; 1.1110x over previous
//
#include <hip/hip_runtime.h>
#include <math.h>

constexpr int NB = 32, NT = 64, ND = 32, NH = 256, NZ = 64, NG = 768;

// ---- ws layout (float offsets; u16 regions noted) --------------------------
constexpr long long OFF_HENC   = 0;                               // [32][256] f32
constexpr long long OFF_H0     = OFF_HENC + NB * NH;              // [32][256] f32
constexpr long long OFF_HDEC   = OFF_H0 + NB * NH;                // [32d][32b][256] f32
constexpr long long OFF_BCMB   = OFF_HDEC + (long long)ND * NB * NH; // [32d][2][256]
constexpr long long OFF_BIN    = OFF_BCMB + ND * 2 * NH;          // [32d][256]
constexpr long long OFF_BHN    = OFF_BIN + ND * NH;               // [32d][256]
constexpr long long OFF_EBC    = OFF_BHN + ND * NH;               // enc biases [4][256]
constexpr long long OFF_WHHIMG = OFF_EBC + 1024;                  // u16: 128 pages x 49152 (192rows x 256k swz)
constexpr long long OFF_WCIMG  = OFF_WHHIMG + (long long)128 * 49152 / 2; // u16: 128 x 6144 (192x32 swz)
constexpr long long OFF_DINIMG = OFF_WCIMG + (long long)128 * 6144 / 2;   // u16: 64 x 1024
constexpr long long OFF_HBF    = OFF_DINIMG + 64 * 1024 / 2;      // u16: 2 par x 32 d x 8192
constexpr long long OFF_EW2    = OFF_HBF + 2 * 32 * 8192 / 2;     // u16: 4 pages x 49152
constexpr long long OFF_EWI2   = OFF_EW2 + 4 * 49152 / 2;         // u16: 4 x 6144
constexpr long long OFF_EXIMG  = OFF_EWI2 + 4 * 6144 / 2;         // u16: 64 x 1024
constexpr long long OFF_EHBF   = OFF_EXIMG + 64 * 1024 / 2;       // u16: 2 par x 8192
constexpr long long OFF_SYNC   = OFF_EHBF + 2 * 8192 / 2;         // 2048 u32: dec flags [32d][16], enc flags @1024
constexpr long long WS_FLOATS  = OFF_SYNC + 2048;                 // ~17.2 MB

typedef __attribute__((ext_vector_type(8))) short bf16x8;
typedef __attribute__((ext_vector_type(4))) float f32x4;
typedef __attribute__((ext_vector_type(4))) unsigned u32x4;

__device__ __forceinline__ float sigm(float x) { return 1.f / (1.f + __expf(-x)); }
__device__ __forceinline__ ushort f2b(float x) {
  unsigned u = __float_as_uint(x);
  unsigned r = (u + 0x7FFFu + ((u >> 16) & 1u)) >> 16;
  return (ushort)r;
}
// device-coherent (bypass L1+local L2, read/write at coherence point), COALESCED
__device__ __forceinline__ void ld_coh3(const void* p0, const void* p1, const void* p2,
                                        u32x4& a, u32x4& b, u32x4& c) {
  asm volatile("global_load_dwordx4 %0, %3, off sc0 sc1\n\t"
               "global_load_dwordx4 %1, %4, off sc0 sc1\n\t"
               "global_load_dwordx4 %2, %5, off sc0 sc1\n\t"
               "s_waitcnt vmcnt(0)"
               : "=v"(a), "=v"(b), "=v"(c)
               : "v"(p0), "v"(p1), "v"(p2));
}
__device__ __forceinline__ u32x4 ld_flags(const void* p) {
  u32x4 r;
  asm volatile("global_load_dwordx4 %0, %1, off sc0 sc1\n\ts_waitcnt vmcnt(0)"
               : "=v"(r) : "v"(p));
  return r;
}
__device__ __forceinline__ void st_coh32(void* p, unsigned v) {
  asm volatile("global_store_dword %0, %1, off sc0 sc1" :: "v"(p), "v"(v) : "memory");
}
__device__ __forceinline__ void drain_vm() {
  asm volatile("s_waitcnt vmcnt(0)" ::: "memory");
}

// ---------------- k_pre: weight images (dec + enc) + biases -------------------
__global__ void k_pre(const float* __restrict__ hWhh, const float* __restrict__ hbih,
                      const float* __restrict__ hbhh, const float* __restrict__ eWhh,
                      const float* __restrict__ eWih, const float* __restrict__ ebih,
                      const float* __restrict__ ebhh, float* __restrict__ ws) {
  int stride = gridDim.x * blockDim.x;
  int idx = blockIdx.x * blockDim.x + threadIdx.x;
  unsigned* img = (unsigned*)(ws + OFF_WHHIMG);
  for (int i = idx; i < 128 * 24576; i += stride) {
    int p = i / 24576, lw = i - p * 24576;
    int d = p >> 2, s2 = p & 3;
    int byte = lw * 4;
    int lr = byte >> 9;                        // 0..191
    int nominal = byte ^ ((lr & 7) << 4);
    int k0 = (nominal & 511) >> 1;
    int g = (lr >> 6) * 256 + s2 * 64 + (lr & 63);
    const float* src = hWhh + ((long long)(d * NG + g)) * NH + k0;
    img[i] = (unsigned)f2b(src[0]) | ((unsigned)f2b(src[1]) << 16);
  }
  for (int i = idx; i < ND * NH; i += stride) {
    int d = i >> 8, j = i & 255;
    const float* bi = hbih + d * NG;
    const float* bh = hbhh + d * NG;
    ws[OFF_BCMB + d * 512 + j]       = bi[j] + bh[j];
    ws[OFF_BCMB + d * 512 + 256 + j] = bi[256 + j] + bh[256 + j];
    ws[OFF_BIN + i] = bi[512 + j];
    ws[OFF_BHN + i] = bh[512 + j];
  }
  unsigned* eimg = (unsigned*)(ws + OFF_EW2);
  for (int i = idx; i < 4 * 24576; i += stride) {
    int s2 = i / 24576, lw = i - s2 * 24576;
    int byte = lw * 4;
    int lr = byte >> 9;
    int nominal = byte ^ ((lr & 7) << 4);
    int k0 = (nominal & 511) >> 1;
    int g = (lr >> 6) * 256 + s2 * 64 + (lr & 63);
    const float* src = eWhh + (long long)g * NH + k0;
    eimg[i] = (unsigned)f2b(src[0]) | ((unsigned)f2b(src[1]) << 16);
  }
  unsigned* eimg2 = (unsigned*)(ws + OFF_EWI2);
  for (int i = idx; i < 4 * 3072; i += stride) {
    int s2 = i / 3072, lw = i - s2 * 3072;
    int byte = lw * 4;
    int lr = byte >> 6;
    int nominal = byte ^ ((lr & 3) << 4);
    int dd0 = (nominal & 63) >> 1;
    int g = (lr >> 6) * 256 + s2 * 64 + (lr & 63);
    const float* src = eWih + g * 32 + dd0;
    eimg2[i] = (unsigned)f2b(src[0]) | ((unsigned)f2b(src[1]) << 16);
  }
  for (int i = idx; i < 256; i += stride) {
    ws[OFF_EBC + i]       = ebih[i] + ebhh[i];
    ws[OFF_EBC + 256 + i] = ebih[256 + i] + ebhh[256 + i];
    ws[OFF_EBC + 512 + i] = ebih[512 + i];
    ws[OFF_EBC + 768 + i] = ebhh[512 + i];
  }
}

// ---------------- k_wcomb: Wcomb[d][g][dd] = sum_h Wih[g,h]*Win[dd,h] --------
__global__ __launch_bounds__(256)
void k_wcomb(const float* __restrict__ Win, const float* __restrict__ hWih,
             float* __restrict__ ws) {
  __shared__ float wd_s[32 * 257];
  __shared__ float wih_s[32 * 257];
  int blk = blockIdx.x;            // 768 = 32 d x 24 gsec
  int d = blk / 24, gsec = blk - d * 24;
  int tid = threadIdx.x;
  for (int i = tid; i < 32 * 256; i += 256) {
    int r = i >> 8, h = i & 255;
    wd_s[r * 257 + h]  = Win[((long long)(d * 32 + r)) * 256 + h];
    wih_s[r * 257 + h] = hWih[((long long)(d * NG + gsec * 32 + r)) * 256 + h];
  }
  __syncthreads();
  ushort* wcimg = (ushort*)(ws + OFF_WCIMG);
  for (int o = tid; o < 1024; o += 256) {
    int gl = o >> 5, dd = o & 31;
    float acc = 0.f;
    #pragma unroll 4
    for (int h = 0; h < 256; ++h) acc += wih_s[gl * 257 + h] * wd_s[dd * 257 + h];
    int g = gsec * 32 + gl;
    int s2 = (g & 255) >> 6, lr = (g >> 8) * 64 + (g & 63);
    int off = (lr * 64 + dd * 2) ^ ((lr & 3) << 4);
    wcimg[(d * 4 + s2) * 6144 + (off >> 1)] = f2b(acc);
  }
}

// ---------------- k_misc: out init + din/x images + EHBF0 + flags zero --------
__global__ void k_misc(const float* __restrict__ xp, const float* __restrict__ xc,
                       const float* __restrict__ fcb, float* __restrict__ ws,
                       float* __restrict__ out) {
  int idx = blockIdx.x * blockDim.x + threadIdx.x;   // 0..137215
  if (idx < 65536) {
    out[idx] = fcb[idx & 31];
  } else if (idx < 98304) {
    int i2 = idx - 65536;                      // din image
    int t = i2 >> 9, lw = i2 & 511;
    int byte = lw * 4;
    int b = byte >> 6;
    int nominal = byte ^ ((b & 3) << 4);
    int dd0 = (nominal & 63) >> 1;
    float v0, v1;
    if (t == 0) { v0 = xp[(b * NT + 63) * ND + dd0]; v1 = xp[(b * NT + 63) * ND + dd0 + 1]; }
    else { v0 = xc[(b * NT + (t - 1)) * ND + dd0]; v1 = xc[(b * NT + (t - 1)) * ND + dd0 + 1]; }
    ((unsigned*)(ws + OFF_DINIMG))[i2] = (unsigned)f2b(v0) | ((unsigned)f2b(v1) << 16);
  } else if (idx < 131072) {
    int i3 = idx - 98304;                      // enc x image
    int t = i3 >> 9, lw = i3 & 511;
    int byte = lw * 4;
    int b = byte >> 6;
    int nominal = byte ^ ((b & 3) << 4);
    int dd0 = (nominal & 63) >> 1;
    float v0 = xp[(b * NT + t) * ND + dd0];
    float v1 = xp[(b * NT + t) * ND + dd0 + 1];
    ((unsigned*)(ws + OFF_EXIMG))[i3] = (unsigned)f2b(v0) | ((unsigned)f2b(v1) << 16);
  } else if (idx < 135168) {
    ((unsigned*)(ws + OFF_EHBF))[idx - 131072] = 0;   // enc h parity-0 = 0
  } else {
    ((unsigned*)(ws + OFF_SYNC))[idx - 135168] = 0;   // flags
  }
}

// ---------------- k_enc4: persistent encoder, 4 j-slice blocks ----------------
__global__ __launch_bounds__(384)
void k_enc4(float* __restrict__ ws) {
  __shared__ __align__(16) char lds[98304 + 16384];
  __shared__ float rz_s[128 * 33];
  __shared__ float in_s[64 * 33];
  __shared__ float ahn_s[64 * 33];
  __shared__ float henc_s[32 * 65];
  char* l_whh = lds;
  char* l_hbf = lds + 98304;

  const int s2 = blockIdx.x;                   // 0..3
  const int tid = threadIdx.x, lane = tid & 63, w = tid >> 6;

  { // stage weights once
    const uint4* sw = (const uint4*)((const ushort*)(ws + OFF_EW2) + (long long)s2 * 49152);
    uint4* dw = (uint4*)l_whh;
    for (int c = tid; c < 6144; c += 384) dw[c] = sw[c];
  }
  for (int i = tid; i < 32 * 65; i += 384) henc_s[i] = 0.f;

  const ushort* wi_pg = (const ushort*)(ws + OFF_EWI2) + s2 * 6144;
  const float* ebc = ws + OFF_EBC;
  unsigned* flags = (unsigned*)(ws + OFF_SYNC) + 1024;
  const int ct = w & 1, rtw = w >> 1;
  const int colL = lane & 15;
  const int kb = (lane >> 4) * 16;
  const int jbase = s2 * 64;

  for (int t = 0; t < 64; ++t) {
    { // wait for h(t) from all 4 producers (flags >= t)
      unsigned tt = (unsigned)t;
      while (true) {
        u32x4 f = ld_flags(flags);
        if (f.x >= tt && f.y >= tt && f.z >= tt && f.w >= tt) break;
        __builtin_amdgcn_s_sleep(1);
      }
    }
    { // stage h page: coherent coalesced loads
      const char* hs = (const char*)((const ushort*)(ws + OFF_EHBF) + (t & 1) * 8192);
      int c0 = tid, c1 = tid + 384, c2 = tid + 768;
      int c2c = c2 < 1024 ? c2 : 0;
      u32x4 a, b, c;
      ld_coh3(hs + c0 * 16, hs + c1 * 16, hs + c2c * 16, a, b, c);
      u32x4* hd = (u32x4*)l_hbf;
      hd[c0] = a; hd[c1] = b; if (c2 < 1024) hd[c2] = c;
    }
    __syncthreads();

    const ushort* x_pg = (const ushort*)(ws + OFF_EXIMG) + t * 1024;
    #pragma unroll
    for (int i = 0; i < 4; ++i) {
      int rt = rtw + 3 * i;
      int rowW = rt * 16 + colL;
      int rowB = ct * 16 + colL;
      f32x4 ah = {0.f, 0.f, 0.f, 0.f};
      #pragma unroll
      for (int kc = 0; kc < 8; ++kc) {
        int ka = kc * 64 + kb;
        bf16x8 av = *(const bf16x8*)(l_whh + ((rowW * 512 + ka) ^ ((rowW & 7) << 4)));
        bf16x8 bv = *(const bf16x8*)(l_hbf + ((rowB * 512 + ka) ^ ((rowB & 7) << 4)));
        ah = __builtin_amdgcn_mfma_f32_16x16x32_bf16(av, bv, ah, 0, 0, 0);
      }
      f32x4 zero = {0.f, 0.f, 0.f, 0.f};
      bf16x8 aw = *(const bf16x8*)((const char*)wi_pg + ((rowW * 64 + kb) ^ ((rowW & 3) << 4)));
      bf16x8 bd = *(const bf16x8*)((const char*)x_pg + ((rowB * 64 + kb) ^ ((rowB & 3) << 4)));
      f32x4 ai = __builtin_amdgcn_mfma_f32_16x16x32_bf16(aw, bd, zero, 0, 0, 0);
      int r0 = rt * 16 + (lane >> 4) * 4;
      int col = ct * 16 + colL;
      #pragma unroll
      for (int rg = 0; rg < 4; ++rg) {
        int lr = r0 + rg;
        if (lr < 128) rz_s[lr * 33 + col] = ah[rg] + ai[rg];
        else { in_s[(lr - 128) * 33 + col] = ai[rg]; ahn_s[(lr - 128) * 33 + col] = ah[rg]; }
      }
    }
    __syncthreads();

    char* hw = (char*)((ushort*)(ws + OFF_EHBF) + ((t + 1) & 1) * 8192);
    for (int base = 0; base < 1024; base += 384) {
      int o = base + tid;
      if (o < 1024) {
        int bb = o >> 5, jp = o & 31, jl = 2 * jp, jg = jbase + jl;
        float h0n, h1n;
        #pragma unroll
        for (int q = 0; q < 2; ++q) {
          int j = jl + q;
          float pr = rz_s[j * 33 + bb] + ebc[jg + q];
          float pz = rz_s[(64 + j) * 33 + bb] + ebc[256 + jg + q];
          float pni = in_s[j * 33 + bb] + ebc[512 + jg + q];
          float pnh = ahn_s[j * 33 + bb] + ebc[768 + jg + q];
          float r = sigm(pr), u = sigm(pz);
          float n = tanhf(pni + r * pnh);
          float hold = henc_s[bb * 65 + j];
          float hv = (1.f - u) * n + u * hold;
          henc_s[bb * 65 + j] = hv;
          if (q == 0) h0n = hv; else h1n = hv;
        }
        int bo = (bb * 512 + jg * 2) ^ ((bb & 7) << 4);
        st_coh32(hw + bo, (unsigned)f2b(h0n) | ((unsigned)f2b(h1n) << 16));
      }
    }
    drain_vm();        // inline-asm stores complete (compiler can't track them)
    __syncthreads();
    if (tid == 0) st_coh32(flags + s2, (unsigned)(t + 1));
  }
  // final hidden
  for (int o = tid; o < 2048; o += 384) {
    int bb = o >> 6, jl = o & 63;
    ws[OFF_HENC + bb * 256 + jbase + jl] = henc_s[bb * 65 + jl];
  }
}

// ---------------- latent ------------------------------------------------------
__global__ __launch_bounds__(256)
void k_latent(const float* __restrict__ muw, const float* __restrict__ mub,
              const float* __restrict__ lsw, const float* __restrict__ lsb,
              const float* __restrict__ refw, const float* __restrict__ refb,
              const float* __restrict__ eps, float* __restrict__ ws,
              float* __restrict__ out) {
  __shared__ float hs[NH];
  __shared__ float mu_s[NZ];
  __shared__ float ls_s[NZ];
  __shared__ float zs[NZ];
  int b = blockIdx.x, tid = threadIdx.x;
  hs[tid] = ws[OFF_HENC + b * NH + tid];
  __syncthreads();
  if (tid < 128) {
    int zi = tid & 63;
    const float* w = (tid < 64 ? muw : lsw) + zi * NH;
    float acc = 0.f;
    #pragma unroll 4
    for (int k = 0; k < NH; ++k) acc += w[k] * hs[k];
    if (tid < 64) {
      acc += mub[zi];
      out[NB * NT * ND + b * NZ + zi] = acc;
      mu_s[zi] = acc;
    } else {
      acc += lsb[zi];
      out[NB * NT * ND + NB * NZ + b * NZ + zi] = acc;
      ls_s[zi] = acc;
    }
  }
  __syncthreads();
  if (tid < 64) zs[tid] = mu_s[tid] + eps[b * NZ + tid] * __expf(ls_s[tid]);
  __syncthreads();
  {
    const float* w = refw + tid * NZ;
    float acc = 0.f;
    #pragma unroll 4
    for (int q = 0; q < NZ; ++q) acc += w[q] * zs[q];
    ws[OFF_H0 + b * NH + tid] = tanhf(acc + refb[tid]);
  }
}

// ---------------- k_hbf0: h0 -> dec h pages parity 0 --------------------------
__global__ void k_hbf0(float* __restrict__ ws) {
  int idx = blockIdx.x * blockDim.x + threadIdx.x;   // 32 x 4096 dwords
  int d = idx >> 12, lw = idx & 4095;
  int byte = lw * 4;
  int bb = byte >> 9;
  int nominal = byte ^ ((bb & 7) << 4);
  int j0 = (nominal & 511) >> 1;
  const float* h0 = ws + OFF_H0 + bb * 256;
  ((unsigned*)(ws + OFF_HBF))[d * 4096 + lw] =
      (unsigned)f2b(h0[j0]) | ((unsigned)f2b(h0[j0 + 1]) << 16);
}

// ---------------- k_dec: persistent decoder, 128 blocks = 4 slices x 32 heads -
__global__ __launch_bounds__(384)
void k_dec(const float* __restrict__ fcw, float* __restrict__ ws,
           float* __restrict__ out) {
  __shared__ __align__(16) char lds[98304 + 16384];
  __shared__ float rz_s[128 * 33];
  __shared__ float in_s[64 * 33];
  __shared__ float ahn_s[64 * 33];
  char* l_whh = lds;
  char* l_hbf = lds + 98304;

  const int d = blockIdx.x & 31, s2 = blockIdx.x >> 5;
  const int tid = threadIdx.x, lane = tid & 63, w = tid >> 6;

  { // stage weights once
    const uint4* sw = (const uint4*)((const ushort*)(ws + OFF_WHHIMG) + (long long)(d * 4 + s2) * 49152);
    uint4* dw = (uint4*)l_whh;
    for (int c = tid; c < 6144; c += 384) dw[c] = sw[c];
  }

  const ushort* wc_pg = (const ushort*)(ws + OFF_WCIMG) + (d * 4 + s2) * 6144;
  const float* bcmb = ws + OFF_BCMB + d * 512;
  const float* bin  = ws + OFF_BIN + d * 256;
  const float* bhn  = ws + OFF_BHN + d * 256;
  float* hdec = ws + OFF_HDEC + (long long)d * NB * NH;
  const float* h0 = ws + OFF_H0;
  unsigned* flags = (unsigned*)(ws + OFF_SYNC) + d * 16;
  const int ct = w & 1, rtw = w >> 1;
  const int colL = lane & 15;
  const int kb = (lane >> 4) * 16;
  const int jbase = s2 * 64;

  for (int t = 0; t < 64; ++t) {
    { // wait for h(t) from this head's 4 producers
      unsigned tt = (unsigned)t;
      while (true) {
        u32x4 f = ld_flags(flags);
        if (f.x >= tt && f.y >= tt && f.z >= tt && f.w >= tt) break;
        __builtin_amdgcn_s_sleep(1);
      }
    }
    { // stage h page: coherent coalesced loads
      const char* hs = (const char*)((const ushort*)(ws + OFF_HBF) + ((t & 1) * 32 + d) * 8192);
      int c0 = tid, c1 = tid + 384, c2 = tid + 768;
      int c2c = c2 < 1024 ? c2 : 0;
      u32x4 a, b, c;
      ld_coh3(hs + c0 * 16, hs + c1 * 16, hs + c2c * 16, a, b, c);
      u32x4* hd = (u32x4*)l_hbf;
      hd[c0] = a; hd[c1] = b; if (c2 < 1024) hd[c2] = c;
    }
    __syncthreads();

    const ushort* din_pg = (const ushort*)(ws + OFF_DINIMG) + t * 1024;
    #pragma unroll
    for (int i = 0; i < 4; ++i) {
      int rt = rtw + 3 * i;
      int rowW = rt * 16 + colL;
      int rowB = ct * 16 + colL;
      f32x4 ah = {0.f, 0.f, 0.f, 0.f};
      #pragma unroll
      for (int kc = 0; kc < 8; ++kc) {
        int ka = kc * 64 + kb;
        bf16x8 av = *(const bf16x8*)(l_whh + ((rowW * 512 + ka) ^ ((rowW & 7) << 4)));
        bf16x8 bv = *(const bf16x8*)(l_hbf + ((rowB * 512 + ka) ^ ((rowB & 7) << 4)));
        ah = __builtin_amdgcn_mfma_f32_16x16x32_bf16(av, bv, ah, 0, 0, 0);
      }
      f32x4 zero = {0.f, 0.f, 0.f, 0.f};
      bf16x8 aw = *(const bf16x8*)((const char*)wc_pg + ((rowW * 64 + kb) ^ ((rowW & 3) << 4)));
      bf16x8 bd = *(const bf16x8*)((const char*)din_pg + ((rowB * 64 + kb) ^ ((rowB & 3) << 4)));
      f32x4 ai = __builtin_amdgcn_mfma_f32_16x16x32_bf16(aw, bd, zero, 0, 0, 0);
      int r0 = rt * 16 + (lane >> 4) * 4;
      int col = ct * 16 + colL;
      #pragma unroll
      for (int rg = 0; rg < 4; ++rg) {
        int lr = r0 + rg;
        if (lr < 128) rz_s[lr * 33 + col] = ah[rg] + ai[rg];
        else { in_s[(lr - 128) * 33 + col] = ai[rg]; ahn_s[(lr - 128) * 33 + col] = ah[rg]; }
      }
    }
    __syncthreads();

    char* hw = (char*)((ushort*)(ws + OFF_HBF) + (((t + 1) & 1) * 32 + d) * 8192);
    for (int base = 0; base < 1024; base += 384) {
      int o = base + tid;
      if (o < 1024) {
        int bb = o >> 5, jp = o & 31, jl = 2 * jp, jg = jbase + jl;
        float h0n, h1n;
        #pragma unroll
        for (int q = 0; q < 2; ++q) {
          int j = jl + q;
          float pr = rz_s[j * 33 + bb] + bcmb[jg + q];
          float pz = rz_s[(64 + j) * 33 + bb] + bcmb[256 + jg + q];
          float pni = in_s[j * 33 + bb] + bin[jg + q];
          float pnh = ahn_s[j * 33 + bb] + bhn[jg + q];
          float r = sigm(pr), u = sigm(pz);
          float n = tanhf(pni + r * pnh);
          float hold = (t == 0) ? h0[bb * 256 + jg + q] : hdec[bb * 256 + jg + q];
          float hv = (1.f - u) * n + u * hold;
          hdec[bb * 256 + jg + q] = hv;
          in_s[j * 33 + bb] = hv;               // reuse in_s as hnew for fc
          if (q == 0) h0n = hv; else h1n = hv;
        }
        int bo = (bb * 512 + jg * 2) ^ ((bb & 7) << 4);
        st_coh32(hw + bo, (unsigned)f2b(h0n) | ((unsigned)f2b(h1n) << 16));
      }
    }
    __syncthreads();

    if (tid < 32) {
      const float* fw = fcw + d * 256 + jbase;
      float acc = 0.f;
      #pragma unroll
      for (int jl = 0; jl < 64; ++jl) acc += in_s[jl * 33 + tid] * fw[jl];
      atomicAdd(&out[(tid * NT + t) * ND + d], acc);
    }
    drain_vm();        // inline-asm h stores complete before flagging
    __syncthreads();
    if (tid == 0) st_coh32(flags + s2, (unsigned)(t + 1));
  }
}

extern "C" void kernel_launch(void* const* d_in, const int* in_sizes, int n_in,
                              void* d_out, int out_size, void* d_ws, size_t ws_size,
                              hipStream_t stream) {
  const float* x_past = (const float*)d_in[0];
  const float* x_curr = (const float*)d_in[1];
  const float* eps    = (const float*)d_in[2];
  const float* eWih   = (const float*)d_in[3];
  const float* ebih   = (const float*)d_in[4];
  const float* eWhh   = (const float*)d_in[5];
  const float* ebhh   = (const float*)d_in[6];
  const float* muw    = (const float*)d_in[7];
  const float* mub    = (const float*)d_in[8];
  const float* lsw    = (const float*)d_in[9];
  const float* lsb    = (const float*)d_in[10];
  const float* refw   = (const float*)d_in[11];
  const float* refb   = (const float*)d_in[12];
  const float* Win    = (const float*)d_in[13];
  const float* hWih   = (const float*)d_in[14];
  const float* hbih   = (const float*)d_in[15];
  const float* hWhh   = (const float*)d_in[16];
  const float* hbhh   = (const float*)d_in[17];
  const float* fcw    = (const float*)d_in[18];
  const float* fcb    = (const float*)d_in[19];
  float* ws  = (float*)d_ws;
  float* out = (float*)d_out;

  if (ws_size < (size_t)WS_FLOATS * 4) return;

  k_pre   <<<2048, 256, 0, stream>>>(hWhh, hbih, hbhh, eWhh, eWih, ebih, ebhh, ws);
  k_wcomb <<<768, 256, 0, stream>>>(Win, hWih, ws);
  k_misc  <<<536, 256, 0, stream>>>(x_past, x_curr, fcb, ws, out);
  k_enc4  <<<4, 384, 0, stream>>>(ws);
  k_latent<<<NB, 256, 0, stream>>>(muw, mub, lsw, lsb, refw, refb, eps, ws, out);
  k_hbf0  <<<512, 256, 0, stream>>>(ws);
  k_dec   <<<128, 384, 0, stream>>>(fcw, ws, out);
}